// Round 7
// baseline (251.428 us; speedup 1.0000x reference)
//
#include <hip/hip_runtime.h>
#include <hip/hip_bf16.h>
#include <stdint.h>

// B=16, S=512, D=512, H=8, DH=64. Float tensors fp32; mask int32; out fp32.
// Internals: bf16 MFMA operands, fp32 accumulation.

typedef __hip_bfloat16 bf16;
typedef __bf16 bf16x8 __attribute__((ext_vector_type(8)));
typedef float f32x4 __attribute__((ext_vector_type(4)));

#define MFMA16(a, b, c) __builtin_amdgcn_mfma_f32_16x16x32_bf16((a), (b), (c), 0, 0, 0)
// Compiler-only fence: blocks LLVM from reordering LDS ops across it (the r5
// NaN was a hoisted cross-lane ds_read); emits ZERO instructions, so global
// loads stay in flight (unlike __syncthreads' vmcnt(0) drain — the r6 regression).
// HW executes a wave's DS ops in order, so this suffices for 1-wave blocks.
#define WAVE_LDS_FENCE() asm volatile("" ::: "memory")

static __device__ __forceinline__ bf16 f2b(float v) { return __float2bfloat16(v); }
static __device__ __forceinline__ bf16x8 ld8(const bf16* p) { return *(const bf16x8*)p; }
static __device__ __forceinline__ uint16_t f2bu(float v) {
  return __hip_bfloat16_raw(__float2bfloat16(v)).x;
}

// ---------------------------------------------------------------- transpose + cast
__global__ __launch_bounds__(256) void transpose512(
    const float* __restrict__ W0, const float* __restrict__ W1,
    const float* __restrict__ W2, const float* __restrict__ W3,
    bf16* __restrict__ T0, bf16* __restrict__ T1,
    bf16* __restrict__ T2, bf16* __restrict__ T3) {
  __shared__ float t[32][33];
  const float* src; bf16* dst;
  switch (blockIdx.z) {
    case 0: src = W0; dst = T0; break;
    case 1: src = W1; dst = T1; break;
    case 2: src = W2; dst = T2; break;
    default: src = W3; dst = T3; break;
  }
  int tx = threadIdx.x, ty = threadIdx.y;  // 32 x 8
  int n0 = blockIdx.x * 32, k0 = blockIdx.y * 32;
#pragma unroll
  for (int i = 0; i < 4; i++) {
    int kk = ty * 4 + i;
    t[kk][tx] = src[(k0 + kk) * 512 + n0 + tx];
  }
  __syncthreads();
#pragma unroll
  for (int i = 0; i < 4; i++) {
    int nn = ty * 4 + i;
    dst[(n0 + nn) * 512 + k0 + tx] = f2b(t[tx][nn]);
  }
}

// ---------------------------------------------------------------- mask -> bitmask
__global__ __launch_bounds__(256) void mask_pack(const int* __restrict__ mask,
                                                 uint32_t* __restrict__ bits) {
  size_t t = (size_t)blockIdx.x * 256 + threadIdx.x;
  int mv = mask[t];
  unsigned long long bal = __ballot(mv != 0);
  if ((threadIdx.x & 63) == 0) {
    ((unsigned long long*)bits)[t >> 6] = bal;
  }
}

// ---------------------------------------------------------------- LayerNorm(x) -> h (bf16)
__global__ __launch_bounds__(256) void ln_rows(
    const float* __restrict__ x, const float* __restrict__ g,
    const float* __restrict__ be, bf16* __restrict__ h) {
  int row = blockIdx.x;
  int tid = threadIdx.x;
  const float* xr = x + (size_t)row * 512;
  float v0 = xr[tid], v1 = xr[tid + 256];
  float s = v0 + v1, s2 = v0 * v0 + v1 * v1;
#pragma unroll
  for (int m = 1; m < 64; m <<= 1) {
    s += __shfl_xor(s, m);
    s2 += __shfl_xor(s2, m);
  }
  __shared__ float rs[4], rs2[4];
  int w = tid >> 6;
  if ((tid & 63) == 0) { rs[w] = s; rs2[w] = s2; }
  __syncthreads();
  s = rs[0] + rs[1] + rs[2] + rs[3];
  s2 = rs2[0] + rs2[1] + rs2[2] + rs2[3];
  float mean = s * (1.0f / 512.0f);
  float var = s2 * (1.0f / 512.0f) - mean * mean;
  float rstd = rsqrtf(var + 1e-5f);
  bf16* hr = h + (size_t)row * 512;
  hr[tid] = f2b((v0 - mean) * rstd * g[tid] + be[tid]);
  hr[tid + 256] = f2b((v1 - mean) * rstd * g[tid + 256] + be[tid + 256]);
}

// ---------------------------------------------------------------- QKV GEMM (unchanged)
__global__ __launch_bounds__(256) void gemm_qkv(
    const bf16* __restrict__ hm,
    const bf16* __restrict__ WT0, const bf16* __restrict__ WT1, const bf16* __restrict__ WT2,
    const float* __restrict__ bq, const float* __restrict__ bk, const float* __restrict__ bv,
    bf16* __restrict__ outq, bf16* __restrict__ outk, bf16* __restrict__ outvT) {
  const int sel = blockIdx.z;
  const bf16* WT = sel == 0 ? WT0 : (sel == 1 ? WT1 : WT2);
  const float* bias = sel == 0 ? bq : (sel == 1 ? bk : bv);
  __shared__ __align__(16) bf16 As[128][40];
  __shared__ __align__(16) bf16 Bs[128][40];
  int tid = threadIdx.x;
  int w = tid >> 6, lane = tid & 63, q4 = lane >> 4, l16 = lane & 15;
  int wr = w >> 1, wc = w & 1;
  int m0 = blockIdx.x * 128, n0 = blockIdx.y * 128;
  f32x4 acc[4][4];
#pragma unroll
  for (int i = 0; i < 4; i++)
#pragma unroll
    for (int j = 0; j < 4; j++) acc[i][j] = (f32x4){0.f, 0.f, 0.f, 0.f};

  for (int kc = 0; kc < 16; kc++) {
    int k0 = kc * 32;
#pragma unroll
    for (int u = tid; u < 512; u += 256) {
      int row = u >> 2, c8 = (u & 3) * 8;
      *(bf16x8*)&As[row][c8] = ld8(&hm[(size_t)(m0 + row) * 512 + k0 + c8]);
      *(bf16x8*)&Bs[row][c8] = ld8(&WT[(size_t)(n0 + row) * 512 + k0 + c8]);
    }
    __syncthreads();
    bf16x8 af[4], bfr[4];
#pragma unroll
    for (int rt = 0; rt < 4; rt++) af[rt] = ld8(&As[wr * 64 + rt * 16 + l16][q4 * 8]);
#pragma unroll
    for (int nt = 0; nt < 4; nt++) bfr[nt] = ld8(&Bs[wc * 64 + nt * 16 + l16][q4 * 8]);
#pragma unroll
    for (int rt = 0; rt < 4; rt++)
#pragma unroll
      for (int nt = 0; nt < 4; nt++) acc[rt][nt] = MFMA16(af[rt], bfr[nt], acc[rt][nt]);
    __syncthreads();
  }

#pragma unroll
  for (int rt = 0; rt < 4; rt++) {
    int mbase = m0 + wr * 64 + rt * 16 + q4 * 4;
    int b = mbase >> 9, s0 = mbase & 511;
#pragma unroll
    for (int nt = 0; nt < 4; nt++) {
      int n = n0 + wc * 64 + nt * 16 + l16;
      float bsv = bias[n];
      int hh = n >> 6, dh = n & 63;
      if (sel == 2) {
        union { bf16 q[4]; uint2 u; } pk;
#pragma unroll
        for (int r = 0; r < 4; r++) pk.q[r] = f2b(acc[rt][nt][r] + bsv);
        *(uint2*)(outvT + ((size_t)((b * 8 + hh) * 64 + dh)) * 512 + s0) = pk.u;
      } else {
        bf16* dst = sel == 0 ? outq : outk;
        float scale = sel == 0 ? 0.125f : 1.0f;
#pragma unroll
        for (int r = 0; r < 4; r++)
          dst[((size_t)((b * 8 + hh) * 512 + s0 + r)) * 64 + dh] =
              f2b((acc[rt][nt][r] + bsv) * scale);
      }
    }
  }
}

// ---------------------------------------------------------------- fused attention v6
// One wave/block, 16 q-rows, 512 keys. Recompute strategy: pass A = QK^T for
// LN stats only; pass B = recompute per 32-key chunk, LN+mask+exp, cross-lane
// transpose through 1.2 KB LDS (compiler-fence only — no vmcnt drain), PV MFMA.
// LDS ~3.5 KB -> ~16 single-wave blocks/CU. XCD swizzle keeps k/v L2-local.
__global__ __launch_bounds__(64, 4) void attn_fused(
    const bf16* __restrict__ q, const bf16* __restrict__ k, const bf16* __restrict__ vT,
    const uint32_t* __restrict__ bits, const float* __restrict__ lg,
    const float* __restrict__ lb, bf16* __restrict__ ctx) {
  const int id = blockIdx.x;             // 0..4095
  const int xcd = id & 7;
  const int j = id >> 3;                 // 0..511
  const int mt = j & 31;
  const int bh = ((j >> 5) << 3) | xcd;  // bh%8 == xcd
  const int m0 = mt * 16;
  const int b = bh >> 3, hh = bh & 7;
  const int lane = threadIdx.x;
  const int q4 = lane >> 4, l16 = lane & 15;

  __shared__ uint16_t PB[2][32][18];   // per-chunk unnormalized probs (bf16 bits)
  __shared__ uint32_t sbits[16][16];   // mask bits: [row][key dword]

  // stage mask bits
  {
    const uint4* gb = (const uint4*)(bits + ((size_t)b * 512 + m0) * 16);
    uint4 t = gb[lane];
    int rr = lane >> 2, cc = (lane & 3) * 4;
    sbits[rr][cc] = t.x; sbits[rr][cc + 1] = t.y;
    sbits[rr][cc + 2] = t.z; sbits[rr][cc + 3] = t.w;
  }
  __syncthreads();  // once per kernel: staging -> cross-lane reads

  const bf16* qb = q + ((size_t)bh * 512 + m0) * 64;
  const bf16* kb = k + (size_t)bh * 512 * 64;
  bf16x8 aq0 = ld8(qb + (size_t)l16 * 64 + q4 * 8);
  bf16x8 aq1 = ld8(qb + (size_t)l16 * 64 + 32 + q4 * 8);

  // ---- pass A: stats only (no score storage)
  float s[4] = {0.f, 0.f, 0.f, 0.f}, s2[4] = {0.f, 0.f, 0.f, 0.f};
#pragma unroll
  for (int nt = 0; nt < 32; nt++) {
    const bf16* kp = kb + (size_t)(nt * 16 + l16) * 64;
    bf16x8 b0 = ld8(kp + q4 * 8);
    bf16x8 b1 = ld8(kp + 32 + q4 * 8);
    f32x4 acc = (f32x4){0.f, 0.f, 0.f, 0.f};
    acc = MFMA16(aq0, b0, acc);
    acc = MFMA16(aq1, b1, acc);
#pragma unroll
    for (int r = 0; r < 4; r++) {
      float v = acc[r];
      s[r] += v;
      s2[r] += v * v;
    }
  }
  float mean[4], rstd[4];
#pragma unroll
  for (int r = 0; r < 4; r++) {
    float a = s[r], a2 = s2[r];
#pragma unroll
    for (int mm = 1; mm < 16; mm <<= 1) {
      a += __shfl_xor(a, mm);
      a2 += __shfl_xor(a2, mm);
    }
    float mu = a * (1.0f / 512.0f);
    float var = a2 * (1.0f / 512.0f) - mu * mu;
    mean[r] = mu;
    rstd[r] = rsqrtf(var + 1e-5f);
  }

  // ---- pass B: recompute scores per 32-key chunk, LN+mask+exp, PV
  const bf16* vb = vT + (size_t)bh * 64 * 512;
  f32x4 o[4];
#pragma unroll
  for (int nt = 0; nt < 4; nt++) o[nt] = (f32x4){0.f, 0.f, 0.f, 0.f};
  float se[4] = {0.f, 0.f, 0.f, 0.f};

#pragma unroll
  for (int c = 0; c < 16; c++) {
    const int buf = c & 1;
#pragma unroll
    for (int kg = 0; kg < 2; kg++) {
      const int key = c * 32 + kg * 16 + l16;
      const bf16* kp = kb + (size_t)key * 64;
      bf16x8 b0 = ld8(kp + q4 * 8);
      bf16x8 b1 = ld8(kp + 32 + q4 * 8);
      f32x4 acc = (f32x4){0.f, 0.f, 0.f, 0.f};
      acc = MFMA16(aq0, b0, acc);
      acc = MFMA16(aq1, b1, acc);
      float g = lg[key], be = lb[key];
      uint16_t p[4];
#pragma unroll
      for (int r = 0; r < 4; r++) {
        uint32_t mw = sbits[q4 * 4 + r][c];
        float v = (acc[r] - mean[r]) * rstd[r] * g + be;
        v = ((mw >> (kg * 16 + l16)) & 1u) ? v : -1.0e9f;
        float pf = __expf(v);
        se[r] += pf;
        p[r] = f2bu(pf);
      }
      *(uint32_t*)&PB[buf][kg * 16 + l16][q4 * 4] = (uint32_t)p[0] | ((uint32_t)p[1] << 16);
      *(uint32_t*)&PB[buf][kg * 16 + l16][q4 * 4 + 2] = (uint32_t)p[2] | ((uint32_t)p[3] << 16);
    }
    WAVE_LDS_FENCE();  // compile-time only: ds_write -> cross-lane ds_read order
    union { uint16_t u[8]; bf16x8 v; } af;
#pragma unroll
    for (int jj = 0; jj < 8; jj++) af.u[jj] = PB[buf][q4 * 8 + jj][l16];
    WAVE_LDS_FENCE();  // keep next chunk's writes below these reads (WAR)
#pragma unroll
    for (int nt = 0; nt < 4; nt++) {
      bf16x8 bv8 = ld8(vb + (size_t)(nt * 16 + l16) * 512 + c * 32 + q4 * 8);
      o[nt] = MFMA16(af.v, bv8, o[nt]);
    }
  }

  float inv[4];
#pragma unroll
  for (int r = 0; r < 4; r++) {
    float a = se[r];
#pragma unroll
    for (int mm = 1; mm < 16; mm <<= 1) a += __shfl_xor(a, mm);
    inv[r] = 1.0f / a;
  }

  bf16* cb = ctx + ((size_t)b * 512 + m0) * 512 + hh * 64;
#pragma unroll
  for (int nt = 0; nt < 4; nt++)
#pragma unroll
    for (int r = 0; r < 4; r++)
      cb[(size_t)(q4 * 4 + r) * 512 + nt * 16 + l16] = f2b(o[nt][r] * inv[r]);
}

// ---------------------------------------------------------------- out proj + residual (fp32 out)
__global__ __launch_bounds__(256) void gemm_out(
    const bf16* __restrict__ ctx, const bf16* __restrict__ WT,
    const float* __restrict__ bd, const float* __restrict__ x, float* __restrict__ out) {
  __shared__ __align__(16) bf16 As[128][40];
  __shared__ __align__(16) bf16 Bs[128][40];
  int tid = threadIdx.x;
  int w = tid >> 6, lane = tid & 63, q4 = lane >> 4, l16 = lane & 15;
  int wr = w >> 1, wc = w & 1;
  int m0 = blockIdx.x * 128, n0 = blockIdx.y * 128;
  f32x4 acc[4][4];
#pragma unroll
  for (int i = 0; i < 4; i++)
#pragma unroll
    for (int j = 0; j < 4; j++) acc[i][j] = (f32x4){0.f, 0.f, 0.f, 0.f};

  for (int kc = 0; kc < 16; kc++) {
    int k0 = kc * 32;
#pragma unroll
    for (int u = tid; u < 512; u += 256) {
      int row = u >> 2, c8 = (u & 3) * 8;
      *(bf16x8*)&As[row][c8] = ld8(&ctx[(size_t)(m0 + row) * 512 + k0 + c8]);
      *(bf16x8*)&Bs[row][c8] = ld8(&WT[(size_t)(n0 + row) * 512 + k0 + c8]);
    }
    __syncthreads();
    bf16x8 af[4], bfr[4];
#pragma unroll
    for (int rt = 0; rt < 4; rt++) af[rt] = ld8(&As[wr * 64 + rt * 16 + l16][q4 * 8]);
#pragma unroll
    for (int nt = 0; nt < 4; nt++) bfr[nt] = ld8(&Bs[wc * 64 + nt * 16 + l16][q4 * 8]);
#pragma unroll
    for (int rt = 0; rt < 4; rt++)
#pragma unroll
      for (int nt = 0; nt < 4; nt++) acc[rt][nt] = MFMA16(af[rt], bfr[nt], acc[rt][nt]);
    __syncthreads();
  }
#pragma unroll
  for (int rt = 0; rt < 4; rt++) {
    int mbase = m0 + wr * 64 + rt * 16 + q4 * 4;
#pragma unroll
    for (int nt = 0; nt < 4; nt++) {
      int n = n0 + wc * 64 + nt * 16 + l16;
      float bsv = bd[n];
#pragma unroll
      for (int r = 0; r < 4; r++) {
        size_t idx = (size_t)(mbase + r) * 512 + n;
        out[idx] = acc[rt][nt][r] + bsv + x[idx];
      }
    }
  }
}

// ---------------------------------------------------------------- launch
extern "C" void kernel_launch(void* const* d_in, const int* in_sizes, int n_in,
                              void* d_out, int out_size, void* d_ws, size_t ws_size,
                              hipStream_t stream) {
  const float* x = (const float*)d_in[0];
  const int* mask = (const int*)d_in[1];
  const float* ln_g = (const float*)d_in[2];
  const float* ln_b = (const float*)d_in[3];
  const float* lna_g = (const float*)d_in[4];
  const float* lna_b = (const float*)d_in[5];
  const float* Wq = (const float*)d_in[6];
  const float* bq = (const float*)d_in[7];
  const float* Wk = (const float*)d_in[8];
  const float* bk = (const float*)d_in[9];
  const float* Wv = (const float*)d_in[10];
  const float* bv = (const float*)d_in[11];
  const float* Wd = (const float*)d_in[12];
  const float* bd = (const float*)d_in[13];

  char* ws = (char*)d_ws;
  const size_t MB = 1024 * 1024;
  if (ws_size < 44 * MB) return;
  bf16* h = (bf16*)(ws);                 // 8 MB  [8192,512]
  bf16* qd = (bf16*)(ws + 8 * MB);       // 8 MB  [B,H,S,DH]
  bf16* kd = (bf16*)(ws + 16 * MB);      // 8 MB  [B,H,S,DH]
  bf16* vTd = (bf16*)(ws + 24 * MB);     // 8 MB  [B,H,DH,S]
  bf16* ctx = (bf16*)(ws + 32 * MB);     // 8 MB  [B,S,D] bf16
  bf16* WqT = (bf16*)(ws + 40 * MB);
  bf16* WkT = (bf16*)(ws + 40 * MB + 512 * 1024);
  bf16* WvT = (bf16*)(ws + 40 * MB + 1024 * 1024);
  bf16* WdT = (bf16*)(ws + 40 * MB + 1536 * 1024);
  uint32_t* bits = (uint32_t*)(ws + 42 * MB);  // 512 KB

  transpose512<<<dim3(16, 16, 4), dim3(32, 8), 0, stream>>>(Wq, Wk, Wv, Wd, WqT, WkT, WvT, WdT);
  mask_pack<<<16384, 256, 0, stream>>>(mask, bits);
  ln_rows<<<8192, 256, 0, stream>>>(x, ln_g, ln_b, h);
  gemm_qkv<<<dim3(64, 4, 3), 256, 0, stream>>>(h, WqT, WkT, WvT, bq, bk, bv, qd, kd, vTd);
  attn_fused<<<4096, 64, 0, stream>>>(qd, kd, vTd, bits, lna_g, lna_b, ctx);
  gemm_out<<<dim3(64, 4), 256, 0, stream>>>(ctx, WdT, bd, x, (float*)d_out);
}

// Round 8
// 205.000 us; speedup vs baseline: 1.2265x; 1.2265x over previous
//
#include <hip/hip_runtime.h>
#include <hip/hip_bf16.h>
#include <stdint.h>

// B=16, S=512, D=512, H=8, DH=64. Float tensors fp32; mask int32; out fp32.
// Internals: bf16 MFMA operands, fp32 accumulation.

typedef __hip_bfloat16 bf16;
typedef __bf16 bf16x8 __attribute__((ext_vector_type(8)));
typedef float f32x4 __attribute__((ext_vector_type(4)));

#define MFMA16(a, b, c) __builtin_amdgcn_mfma_f32_16x16x32_bf16((a), (b), (c), 0, 0, 0)

static __device__ __forceinline__ bf16 f2b(float v) { return __float2bfloat16(v); }
static __device__ __forceinline__ bf16x8 ld8(const bf16* p) { return *(const bf16x8*)p; }
static __device__ __forceinline__ uint16_t f2bu(float v) {
  return __hip_bfloat16_raw(__float2bfloat16(v)).x;
}
static __device__ __forceinline__ float bu2f(uint32_t u) {
  union { uint32_t i; float f; } c;
  c.i = u << 16;
  return c.f;
}

// ---------------------------------------------------------------- transpose + cast
__global__ __launch_bounds__(256) void transpose512(
    const float* __restrict__ W0, const float* __restrict__ W1,
    const float* __restrict__ W2, const float* __restrict__ W3,
    bf16* __restrict__ T0, bf16* __restrict__ T1,
    bf16* __restrict__ T2, bf16* __restrict__ T3) {
  __shared__ float t[32][33];
  const float* src; bf16* dst;
  switch (blockIdx.z) {
    case 0: src = W0; dst = T0; break;
    case 1: src = W1; dst = T1; break;
    case 2: src = W2; dst = T2; break;
    default: src = W3; dst = T3; break;
  }
  int tx = threadIdx.x, ty = threadIdx.y;  // 32 x 8
  int n0 = blockIdx.x * 32, k0 = blockIdx.y * 32;
#pragma unroll
  for (int i = 0; i < 4; i++) {
    int kk = ty * 4 + i;
    t[kk][tx] = src[(k0 + kk) * 512 + n0 + tx];
  }
  __syncthreads();
#pragma unroll
  for (int i = 0; i < 4; i++) {
    int nn = ty * 4 + i;
    dst[(n0 + nn) * 512 + k0 + tx] = f2b(t[tx][nn]);
  }
}

// ---------------------------------------------------------------- mask -> bitmask
__global__ __launch_bounds__(256) void mask_pack(const int* __restrict__ mask,
                                                 uint32_t* __restrict__ bits) {
  size_t t = (size_t)blockIdx.x * 256 + threadIdx.x;
  int mv = mask[t];
  unsigned long long bal = __ballot(mv != 0);
  if ((threadIdx.x & 63) == 0) {
    ((unsigned long long*)bits)[t >> 6] = bal;
  }
}

// ---------------------------------------------------------------- bit transpose
// tbits[row*16 + l] bit j = mask bit of key (l + 16*j). Lets each attn lane
// hold its 4 rows' mask bits in 4 registers (no LDS, no per-key decode).
__global__ __launch_bounds__(256) void mask_transpose(const uint32_t* __restrict__ bits,
                                                      uint32_t* __restrict__ tbits) {
  int t = blockIdx.x * 256 + threadIdx.x;  // 8192 rows * 16 lanes
  int row = t >> 4, l = t & 15;
  const uint32_t* in = bits + row * 16;
  uint32_t o = 0;
#pragma unroll
  for (int jj = 0; jj < 32; jj++) {
    int key = l + 16 * jj;
    o |= ((in[key >> 5] >> (key & 31)) & 1u) << jj;
  }
  tbits[t] = o;
}

// ---------------------------------------------------------------- LayerNorm(x) -> h (bf16)
__global__ __launch_bounds__(256) void ln_rows(
    const float* __restrict__ x, const float* __restrict__ g,
    const float* __restrict__ be, bf16* __restrict__ h) {
  int row = blockIdx.x;
  int tid = threadIdx.x;
  const float* xr = x + (size_t)row * 512;
  float v0 = xr[tid], v1 = xr[tid + 256];
  float s = v0 + v1, s2 = v0 * v0 + v1 * v1;
#pragma unroll
  for (int m = 1; m < 64; m <<= 1) {
    s += __shfl_xor(s, m);
    s2 += __shfl_xor(s2, m);
  }
  __shared__ float rs[4], rs2[4];
  int w = tid >> 6;
  if ((tid & 63) == 0) { rs[w] = s; rs2[w] = s2; }
  __syncthreads();
  s = rs[0] + rs[1] + rs[2] + rs[3];
  s2 = rs2[0] + rs2[1] + rs2[2] + rs2[3];
  float mean = s * (1.0f / 512.0f);
  float var = s2 * (1.0f / 512.0f) - mean * mean;
  float rstd = rsqrtf(var + 1e-5f);
  bf16* hr = h + (size_t)row * 512;
  hr[tid] = f2b((v0 - mean) * rstd * g[tid] + be[tid]);
  hr[tid + 256] = f2b((v1 - mean) * rstd * g[tid + 256] + be[tid + 256]);
}

// ---------------------------------------------------------------- QKV GEMM (unchanged)
__global__ __launch_bounds__(256) void gemm_qkv(
    const bf16* __restrict__ hm,
    const bf16* __restrict__ WT0, const bf16* __restrict__ WT1, const bf16* __restrict__ WT2,
    const float* __restrict__ bq, const float* __restrict__ bk, const float* __restrict__ bv,
    bf16* __restrict__ outq, bf16* __restrict__ outk, bf16* __restrict__ outvT) {
  const int sel = blockIdx.z;
  const bf16* WT = sel == 0 ? WT0 : (sel == 1 ? WT1 : WT2);
  const float* bias = sel == 0 ? bq : (sel == 1 ? bk : bv);
  __shared__ __align__(16) bf16 As[128][40];
  __shared__ __align__(16) bf16 Bs[128][40];
  int tid = threadIdx.x;
  int w = tid >> 6, lane = tid & 63, q4 = lane >> 4, l16 = lane & 15;
  int wr = w >> 1, wc = w & 1;
  int m0 = blockIdx.x * 128, n0 = blockIdx.y * 128;
  f32x4 acc[4][4];
#pragma unroll
  for (int i = 0; i < 4; i++)
#pragma unroll
    for (int j = 0; j < 4; j++) acc[i][j] = (f32x4){0.f, 0.f, 0.f, 0.f};

  for (int kc = 0; kc < 16; kc++) {
    int k0 = kc * 32;
#pragma unroll
    for (int u = tid; u < 512; u += 256) {
      int row = u >> 2, c8 = (u & 3) * 8;
      *(bf16x8*)&As[row][c8] = ld8(&hm[(size_t)(m0 + row) * 512 + k0 + c8]);
      *(bf16x8*)&Bs[row][c8] = ld8(&WT[(size_t)(n0 + row) * 512 + k0 + c8]);
    }
    __syncthreads();
    bf16x8 af[4], bfr[4];
#pragma unroll
    for (int rt = 0; rt < 4; rt++) af[rt] = ld8(&As[wr * 64 + rt * 16 + l16][q4 * 8]);
#pragma unroll
    for (int nt = 0; nt < 4; nt++) bfr[nt] = ld8(&Bs[wc * 64 + nt * 16 + l16][q4 * 8]);
#pragma unroll
    for (int rt = 0; rt < 4; rt++)
#pragma unroll
      for (int nt = 0; nt < 4; nt++) acc[rt][nt] = MFMA16(af[rt], bfr[nt], acc[rt][nt]);
    __syncthreads();
  }

#pragma unroll
  for (int rt = 0; rt < 4; rt++) {
    int mbase = m0 + wr * 64 + rt * 16 + q4 * 4;
    int b = mbase >> 9, s0 = mbase & 511;
#pragma unroll
    for (int nt = 0; nt < 4; nt++) {
      int n = n0 + wc * 64 + nt * 16 + l16;
      float bsv = bias[n];
      int hh = n >> 6, dh = n & 63;
      if (sel == 2) {
        union { bf16 q[4]; uint2 u; } pk;
#pragma unroll
        for (int r = 0; r < 4; r++) pk.q[r] = f2b(acc[rt][nt][r] + bsv);
        *(uint2*)(outvT + ((size_t)((b * 8 + hh) * 64 + dh)) * 512 + s0) = pk.u;
      } else {
        bf16* dst = sel == 0 ? outq : outk;
        float scale = sel == 0 ? 0.125f : 1.0f;
#pragma unroll
        for (int r = 0; r < 4; r++)
          dst[((size_t)((b * 8 + hh) * 512 + s0 + r)) * 64 + dh] =
              f2b((acc[rt][nt][r] + bsv) * scale);
      }
    }
  }
}

// ---------------------------------------------------------------- fused attention v8
// Block = 256 thr (4 waves) x 64 q-rows x one bh; grid 1024 (XCD-swizzled).
// k/v chunks staged ONCE per block into LDS (coalesced) and shared by all 4
// waves -> L2 fragment traffic drops ~4x per q-row vs one-wave blocks (the
// r3/r4/r7 plateau was effective-L2-BW ~7 TB/s on 16B-strided fragment loads).
// Scores (64 rows x 512 keys, bf16) live in LDS; single k pass; exp in place;
// softmax scale folded into epilogue. One barrier per chunk (double-buffered).
__global__ __launch_bounds__(256, 2) void attn_fused(
    const bf16* __restrict__ q, const bf16* __restrict__ k, const bf16* __restrict__ vT,
    const uint32_t* __restrict__ tbits, const float* __restrict__ lg,
    const float* __restrict__ lb, bf16* __restrict__ ctx) {
  const int id = blockIdx.x;              // 0..1023
  const int xcd = id & 7;
  const int j = id >> 3;                  // 0..127
  const int mt = j & 7;                   // 8 m-tiles of 64 rows
  const int bh = ((j >> 3) << 3) | xcd;   // bh%8 == xcd
  const int m0 = mt * 64;
  const int b = bh >> 3, hh = bh & 7;
  const int tid = threadIdx.x;
  const int w = tid >> 6, lane = tid & 63, q4 = lane >> 4, l16 = lane & 15;

  __shared__ uint16_t ST[512][66];              // 67.6 KB: scores -> probs (bf16 bits)
  __shared__ __align__(16) bf16 SB[2][2560];    // 10 KB: k chunk [32][72] / v chunk [64][40]
  // total 77.8 KB -> 2 blocks/CU

  const bf16* qb = q + ((size_t)bh * 512 + m0 + w * 16) * 64;
  const bf16* kb = k + (size_t)bh * 512 * 64;
  const bf16* vb = vT + (size_t)bh * 64 * 512;

  bf16x8 aq0 = ld8(qb + (size_t)l16 * 64 + q4 * 8);
  bf16x8 aq1 = ld8(qb + (size_t)l16 * 64 + 32 + q4 * 8);

  // per-lane mask bits: row w*16+q4*4+r, keys == l16 (mod 16); bit j <-> key j*16+l16
  uint32_t tb[4];
#pragma unroll
  for (int r = 0; r < 4; r++)
    tb[r] = tbits[((size_t)b * 512 + m0 + w * 16 + q4 * 4 + r) * 16 + l16];

  const int col = w * 16 + q4 * 4;  // this lane's ST column base (its 4 rows)

  // ---- phase 1: QK^T into ST, stats in registers; k staged chunk-wise
  {
    int key0 = tid >> 3, dh8 = (tid & 7) * 8;  // staging slot
    *(bf16x8*)&SB[0][key0 * 72 + dh8] = ld8(kb + (size_t)key0 * 64 + dh8);
  }
  __syncthreads();

  float s[4] = {0.f, 0.f, 0.f, 0.f}, s2[4] = {0.f, 0.f, 0.f, 0.f};
  for (int c = 0; c < 16; c++) {
    const int buf = c & 1;
    if (c < 15) {  // prefetch next chunk into other buffer
      int key0 = tid >> 3, dh8 = (tid & 7) * 8;
      *(bf16x8*)&SB[buf ^ 1][key0 * 72 + dh8] =
          ld8(kb + (size_t)((c + 1) * 32 + key0) * 64 + dh8);
    }
#pragma unroll
    for (int kg = 0; kg < 2; kg++) {
      const bf16* kp = &SB[buf][(kg * 16 + l16) * 72];
      bf16x8 b0 = ld8(kp + q4 * 8);
      bf16x8 b1 = ld8(kp + 32 + q4 * 8);
      f32x4 acc = (f32x4){0.f, 0.f, 0.f, 0.f};
      acc = MFMA16(aq0, b0, acc);
      acc = MFMA16(aq1, b1, acc);
#pragma unroll
      for (int r = 0; r < 4; r++) {
        float v = acc[r];
        s[r] += v;
        s2[r] += v * v;
      }
      int key = c * 32 + kg * 16 + l16;
      *(uint32_t*)&ST[key][col] = (uint32_t)f2bu(acc[0]) | ((uint32_t)f2bu(acc[1]) << 16);
      *(uint32_t*)&ST[key][col + 2] = (uint32_t)f2bu(acc[2]) | ((uint32_t)f2bu(acc[3]) << 16);
    }
    __syncthreads();
  }

  // ---- stats (wave-local 16-lane reduce)
  float mean[4], rstd[4];
#pragma unroll
  for (int r = 0; r < 4; r++) {
    float a = s[r], a2 = s2[r];
#pragma unroll
    for (int mm = 1; mm < 16; mm <<= 1) {
      a += __shfl_xor(a, mm);
      a2 += __shfl_xor(a2, mm);
    }
    float mu = a * (1.0f / 512.0f);
    float var = a2 * (1.0f / 512.0f) - mu * mu;
    mean[r] = mu;
    rstd[r] = rsqrtf(var + 1e-5f);
  }

  // ---- phase 2: LN + mask + exp, in place (same lane, same addresses)
  float se[4] = {0.f, 0.f, 0.f, 0.f};
#pragma unroll
  for (int i = 0; i < 32; i++) {
    int key = i * 16 + l16;
    float g = lg[key], be = lb[key];
    uint32_t d0 = *(uint32_t*)&ST[key][col];
    uint32_t d1 = *(uint32_t*)&ST[key][col + 2];
    float v[4] = {bu2f(d0 & 0xffff), bu2f(d0 >> 16), bu2f(d1 & 0xffff), bu2f(d1 >> 16)};
    uint16_t p[4];
#pragma unroll
    for (int r = 0; r < 4; r++) {
      float t = (v[r] - mean[r]) * rstd[r] * g + be;
      t = ((tb[r] >> i) & 1u) ? t : -1.0e9f;
      float pf = __expf(t);
      se[r] += pf;
      p[r] = f2bu(pf);
    }
    *(uint32_t*)&ST[key][col] = (uint32_t)p[0] | ((uint32_t)p[1] << 16);
    *(uint32_t*)&ST[key][col + 2] = (uint32_t)p[2] | ((uint32_t)p[3] << 16);
  }
  float inv[4];
#pragma unroll
  for (int r = 0; r < 4; r++) {
    float a = se[r];
#pragma unroll
    for (int mm = 1; mm < 16; mm <<= 1) a += __shfl_xor(a, mm);
    inv[r] = 1.0f / a;
  }

  // ---- phase 3: PV; v staged chunk-wise as [dh][key] (64x40 pad)
  {
    int dh = tid >> 2, kk8 = (tid & 3) * 8;
    *(bf16x8*)&SB[0][dh * 40 + kk8] = ld8(vb + (size_t)dh * 512 + kk8);
  }
  __syncthreads();  // also orders all waves' exp writes before PV reads

  f32x4 o[4];
#pragma unroll
  for (int nt = 0; nt < 4; nt++) o[nt] = (f32x4){0.f, 0.f, 0.f, 0.f};

  for (int c = 0; c < 16; c++) {
    const int buf = c & 1;
    if (c < 15) {
      int dh = tid >> 2, kk8 = (tid & 3) * 8;
      *(bf16x8*)&SB[buf ^ 1][dh * 40 + kk8] =
          ld8(vb + (size_t)dh * 512 + (c + 1) * 32 + kk8);
    }
    union { uint16_t u[8]; bf16x8 v; } af;
#pragma unroll
    for (int jj = 0; jj < 8; jj++) af.u[jj] = ST[c * 32 + q4 * 8 + jj][w * 16 + l16];
#pragma unroll
    for (int nt = 0; nt < 4; nt++) {
      bf16x8 bv8 = ld8(&SB[buf][(nt * 16 + l16) * 40 + q4 * 8]);
      o[nt] = MFMA16(af.v, bv8, o[nt]);
    }
    __syncthreads();
  }

  // ---- epilogue: scale by 1/sum, write ctx
  bf16* cb = ctx + ((size_t)b * 512 + m0 + w * 16) * 512 + hh * 64;
#pragma unroll
  for (int nt = 0; nt < 4; nt++)
#pragma unroll
    for (int r = 0; r < 4; r++)
      cb[(size_t)(q4 * 4 + r) * 512 + nt * 16 + l16] = f2b(o[nt][r] * inv[r]);
}

// ---------------------------------------------------------------- out proj + residual (fp32 out)
__global__ __launch_bounds__(256) void gemm_out(
    const bf16* __restrict__ ctx, const bf16* __restrict__ WT,
    const float* __restrict__ bd, const float* __restrict__ x, float* __restrict__ out) {
  __shared__ __align__(16) bf16 As[128][40];
  __shared__ __align__(16) bf16 Bs[128][40];
  int tid = threadIdx.x;
  int w = tid >> 6, lane = tid & 63, q4 = lane >> 4, l16 = lane & 15;
  int wr = w >> 1, wc = w & 1;
  int m0 = blockIdx.x * 128, n0 = blockIdx.y * 128;
  f32x4 acc[4][4];
#pragma unroll
  for (int i = 0; i < 4; i++)
#pragma unroll
    for (int j = 0; j < 4; j++) acc[i][j] = (f32x4){0.f, 0.f, 0.f, 0.f};

  for (int kc = 0; kc < 16; kc++) {
    int k0 = kc * 32;
#pragma unroll
    for (int u = tid; u < 512; u += 256) {
      int row = u >> 2, c8 = (u & 3) * 8;
      *(bf16x8*)&As[row][c8] = ld8(&ctx[(size_t)(m0 + row) * 512 + k0 + c8]);
      *(bf16x8*)&Bs[row][c8] = ld8(&WT[(size_t)(n0 + row) * 512 + k0 + c8]);
    }
    __syncthreads();
    bf16x8 af[4], bfr[4];
#pragma unroll
    for (int rt = 0; rt < 4; rt++) af[rt] = ld8(&As[wr * 64 + rt * 16 + l16][q4 * 8]);
#pragma unroll
    for (int nt = 0; nt < 4; nt++) bfr[nt] = ld8(&Bs[wc * 64 + nt * 16 + l16][q4 * 8]);
#pragma unroll
    for (int rt = 0; rt < 4; rt++)
#pragma unroll
      for (int nt = 0; nt < 4; nt++) acc[rt][nt] = MFMA16(af[rt], bfr[nt], acc[rt][nt]);
    __syncthreads();
  }
#pragma unroll
  for (int rt = 0; rt < 4; rt++) {
    int mbase = m0 + wr * 64 + rt * 16 + q4 * 4;
#pragma unroll
    for (int nt = 0; nt < 4; nt++) {
      int n = n0 + wc * 64 + nt * 16 + l16;
      float bsv = bd[n];
#pragma unroll
      for (int r = 0; r < 4; r++) {
        size_t idx = (size_t)(mbase + r) * 512 + n;
        out[idx] = acc[rt][nt][r] + bsv + x[idx];
      }
    }
  }
}

// ---------------------------------------------------------------- launch
extern "C" void kernel_launch(void* const* d_in, const int* in_sizes, int n_in,
                              void* d_out, int out_size, void* d_ws, size_t ws_size,
                              hipStream_t stream) {
  const float* x = (const float*)d_in[0];
  const int* mask = (const int*)d_in[1];
  const float* ln_g = (const float*)d_in[2];
  const float* ln_b = (const float*)d_in[3];
  const float* lna_g = (const float*)d_in[4];
  const float* lna_b = (const float*)d_in[5];
  const float* Wq = (const float*)d_in[6];
  const float* bq = (const float*)d_in[7];
  const float* Wk = (const float*)d_in[8];
  const float* bk = (const float*)d_in[9];
  const float* Wv = (const float*)d_in[10];
  const float* bv = (const float*)d_in[11];
  const float* Wd = (const float*)d_in[12];
  const float* bd = (const float*)d_in[13];

  char* ws = (char*)d_ws;
  const size_t MB = 1024 * 1024;
  if (ws_size < 44 * MB) return;
  bf16* h = (bf16*)(ws);                 // 8 MB  [8192,512]
  bf16* qd = (bf16*)(ws + 8 * MB);       // 8 MB  [B,H,S,DH]
  bf16* kd = (bf16*)(ws + 16 * MB);      // 8 MB  [B,H,S,DH]
  bf16* vTd = (bf16*)(ws + 24 * MB);     // 8 MB  [B,H,DH,S]
  bf16* ctx = (bf16*)(ws + 32 * MB);     // 8 MB  [B,S,D] bf16
  bf16* WqT = (bf16*)(ws + 40 * MB);
  bf16* WkT = (bf16*)(ws + 40 * MB + 512 * 1024);
  bf16* WvT = (bf16*)(ws + 40 * MB + 1024 * 1024);
  bf16* WdT = (bf16*)(ws + 40 * MB + 1536 * 1024);
  uint32_t* bits = (uint32_t*)(ws + 42 * MB);         // 512 KB
  uint32_t* tbits = (uint32_t*)(ws + 42 * MB + 512 * 1024);  // 512 KB

  transpose512<<<dim3(16, 16, 4), dim3(32, 8), 0, stream>>>(Wq, Wk, Wv, Wd, WqT, WkT, WvT, WdT);
  mask_pack<<<16384, 256, 0, stream>>>(mask, bits);
  mask_transpose<<<512, 256, 0, stream>>>(bits, tbits);
  ln_rows<<<8192, 256, 0, stream>>>(x, ln_g, ln_b, h);
  gemm_qkv<<<dim3(64, 4, 3), 256, 0, stream>>>(h, WqT, WkT, WvT, bq, bk, bv, qd, kd, vTd);
  attn_fused<<<1024, 256, 0, stream>>>(qd, kd, vTd, tbits, lna_g, lna_b, ctx);
  gemm_out<<<dim3(64, 4), 256, 0, stream>>>(ctx, WdT, bd, x, (float*)d_out);
}